// Round 1
// baseline (92876.837 us; speedup 1.0000x reference)
//
#include <hip/hip_runtime.h>
#include <hip/hip_bf16.h>
#include <math.h>

// Weight-stationary persistent LSTM.
// Grid = 8 row-groups (32 batch rows) x 32 unit-slices (8 units + 4 mu + 4 sigma cols).
// Weights live in LDS for the whole kernel; c-state in registers; per-step
// h/z exchange within a row-group via LLC (agent-scope atomics + flags).

#define BATCH 256
#define SEQT  1024
#define DX    128
#define DZ    128
#define UNITS 256
#define G4    1024

#define RG    8      // row groups (blockIdx.x & 7 -> same XCD, locality hint only)
#define CBN   32     // unit-slice blocks per row group
#define MROWS 32     // batch rows per group
#define UB    8      // LSTM units per block
#define NTHR  512

#define ACT_STR 516  // padded activation row stride (floats) -> conflict-free

// LDS float-offset map
#define WG_OFF    0                          // [512][32] gate weights (k x col)
#define WH_OFF    (WG_OFF + 512*32)          // [256][8]  head weights
#define ACT_OFF   (WH_OFF + 256*8)           // [32][516] activations z|x|h
#define GRED_OFF  (ACT_OFF + MROWS*ACT_STR)  // [32][32]  gate partials / totals
#define HSCR_OFF  (GRED_OFF + 32*32)         // [32][8]   head partials
#define MUSIG_OFF (HSCR_OFF + 32*8)          // [32][8]   mu(0..3) sigma(4..7)
#define BG_OFF    (MUSIG_OFF + 32*8)         // [32] gate bias slice
#define BH_OFF    (BG_OFF + 32)              // [8]  head bias slice
#define LDS_FLOATS (BH_OFF + 8)
#define LDS_BYTES  (LDS_FLOATS * 4)          // 146080 B < 160 KiB

__device__ __forceinline__ float ldf(const float* p) { return *p; }
__device__ __forceinline__ float ldf(const __hip_bfloat16* p) { return __bfloat162float(*p); }
__device__ __forceinline__ void stf(float* p, float v) { *p = v; }
__device__ __forceinline__ void stf(__hip_bfloat16* p, float v) { *p = __float2bfloat16(v); }

__device__ __forceinline__ float sigmoidf_(float x) { return 1.0f / (1.0f + expf(-x)); }
__device__ __forceinline__ float softplusf_(float x) {
    float ax = fabsf(x);
    return fmaxf(x, 0.0f) + log1pf(expf(-ax));
}

// ---- exchange state (device globals; no d_ws dependence) ----
__device__ float g_h_ex[2][RG][MROWS][UNITS];   // h(t) in slot t&1
__device__ float g_z_ex[2][RG][MROWS][DZ];      // z(t) in slot t&1
__device__ __align__(128) int g_flag_h[RG][CBN];
__device__ __align__(128) int g_flag_z[RG][CBN];
__device__ int g_abort;

// Probe: bias holds 1024 small values. bf16 words all have exponent < 127;
// fp32 low-mantissa words are ~random -> some word has exponent >= 127.
__global__ void detect_dtype_kernel(const unsigned short* __restrict__ bias_words,
                                    int* __restrict__ flag) {
    __shared__ int any_big;
    if (threadIdx.x == 0) any_big = 0;
    __syncthreads();
    int local = 0;
    for (int i = threadIdx.x; i < 1024; i += 256) {
        unsigned short w = bias_words[i];
        int e = (w >> 7) & 0xFF;
        if (e >= 127) local = 1;
    }
    if (local) atomicOr(&any_big, 1);
    __syncthreads();
    if (threadIdx.x == 0) flag[0] = any_big;
}

__global__ void reset_flags_kernel() {
    int i = threadIdx.x;
    if (i < RG * CBN) {
        __hip_atomic_store(&(&g_flag_h[0][0])[i], -1, __ATOMIC_RELAXED, __HIP_MEMORY_SCOPE_AGENT);
        __hip_atomic_store(&(&g_flag_z[0][0])[i], -1, __ATOMIC_RELAXED, __HIP_MEMORY_SCOPE_AGENT);
    }
    if (i == 0) __hip_atomic_store(&g_abort, 0, __ATOMIC_RELAXED, __HIP_MEMORY_SCOPE_AGENT);
}

__device__ __forceinline__ void wait_group_flags(int* fl, int tval, int tid) {
    if (tid < CBN) {
        int n = 0;
        while (__hip_atomic_load(&fl[tid], __ATOMIC_RELAXED, __HIP_MEMORY_SCOPE_AGENT) < tval) {
            __builtin_amdgcn_s_sleep(2);
            if ((++n & 2047) == 0) {
                if (__hip_atomic_load(&g_abort, __ATOMIC_RELAXED, __HIP_MEMORY_SCOPE_AGENT) != 0) break;
                if (n > 8000000) {   // ~bounded: wrong answer instead of harness hang
                    __hip_atomic_store(&g_abort, 1, __ATOMIC_RELAXED, __HIP_MEMORY_SCOPE_AGENT);
                    break;
                }
            }
        }
    }
    __builtin_amdgcn_fence(__ATOMIC_ACQUIRE, "agent");
    __syncthreads();
}

template <typename T>
__global__ __launch_bounds__(NTHR, 1) void lstm_persist(
    const int* __restrict__ flag, int want,
    const T* __restrict__ inp,   // [B][T][DX]
    const T* __restrict__ K,     // [256][1024]
    const T* __restrict__ R,     // [256][1024]
    const T* __restrict__ bias,  // [1024]
    const T* __restrict__ Wmu,   // [256][128]
    const T* __restrict__ bmu,   // [128]
    const T* __restrict__ Wsig,  // [256][128]
    const T* __restrict__ bsig,  // [128]
    const T* __restrict__ eps,   // [T-1][B][DZ]
    T* __restrict__ out)         // mu [B][T][DZ] then sigma [B][T][DZ]
{
    if (flag[0] != want) return;
    extern __shared__ float lds[];

    const int tid = threadIdx.x;
    const int rg  = blockIdx.x & (RG - 1);
    const int cb  = blockIdx.x >> 3;
    const int u0  = cb * UB;     // first unit of this slice
    const int z0  = cb * 4;      // first head/z column of this slice

    float* Wg    = lds + WG_OFF;
    float* Wh    = lds + WH_OFF;
    float* act   = lds + ACT_OFF;
    float* gred  = lds + GRED_OFF;
    float* hscr  = lds + HSCR_OFF;
    float* musig = lds + MUSIG_OFF;
    float* bg    = lds + BG_OFF;
    float* bh    = lds + BH_OFF;

    // ---- preload weight slices (once per launch) ----
    for (int idx = tid; idx < 512 * 32; idx += NTHR) {
        int k = idx >> 5, c = idx & 31;                 // c = gate*8 + unit_local
        int col = ((c >> 3) << 8) + u0 + (c & 7);       // gate*256 + unit
        float v = (k < 256) ? ldf(K + (size_t)k * G4 + col)
                            : ldf(R + (size_t)(k - 256) * G4 + col);
        Wg[k * 32 + c] = v;
    }
    for (int idx = tid; idx < 256 * 8; idx += NTHR) {
        int k = idx >> 3, hc = idx & 7;
        float v = (hc < 4) ? ldf(Wmu + (size_t)k * DZ + z0 + hc)
                           : ldf(Wsig + (size_t)k * DZ + z0 + (hc - 4));
        Wh[k * 8 + hc] = v;
    }
    if (tid < 32) bg[tid] = ldf(bias + ((tid >> 3) << 8) + u0 + (tid & 7));
    if (tid < 8)  bh[tid] = (tid < 4) ? ldf(bmu + z0 + tid) : ldf(bsig + z0 + tid - 4);

    // zero activation panel (z=0, h=0 at t=0), then stage x(0)
    for (int idx = tid; idx < MROWS * 512; idx += NTHR) {
        int r = idx >> 9, c = idx & 511;
        act[r * ACT_STR + c] = 0.0f;
    }
    __syncthreads();
    {
        int r = tid >> 4, j0 = (tid & 15) * 8;
        const T* ip = inp + (size_t)(rg * MROWS + r) * SEQT * DX + j0;
        float* dx = act + r * ACT_STR + 128 + j0;
        #pragma unroll
        for (int j = 0; j < 8; ++j) dx[j] = ldf(ip + j);
    }
    __syncthreads();

    const int kh = tid >> 8;         // k-half: 0 -> zx (K), 1 -> h (R)
    const int gr = (tid >> 3) & 31;  // row for gate/head phases
    const int cq = tid & 7;          // col-quad within the 32-col slice
    const int kbase = kh * 256;

    float cst = 0.0f;                // cell state for (row=tid>>3, unit=tid&7), tid<256
    const size_t OUT_SIG = (size_t)BATCH * SEQT * DZ;

    for (int t = 0; t < SEQT; ++t) {
        // ---- stage z(t) from row-group exchange (t>=1) ----
        if (t > 0) {
            wait_group_flags(g_flag_z[rg], t, tid);
            int r = tid >> 4, j0 = (tid & 15) * 8;
            const float* zp = &g_z_ex[t & 1][rg][r][j0];
            float* dzp = act + r * ACT_STR + j0;
            #pragma unroll
            for (int j = 0; j < 8; ++j)
                dzp[j] = __hip_atomic_load(zp + j, __ATOMIC_RELAXED, __HIP_MEMORY_SCOPE_AGENT);
            __syncthreads();
        }

        // ---- gates: [32 rows x 512] @ [512 x 32 cols], k split in halves ----
        float a0 = 0.f, a1 = 0.f, a2 = 0.f, a3 = 0.f;
        {
            const float* ap = act + gr * ACT_STR + kbase;
            const float* wp = Wg + kbase * 32 + cq * 4;
            #pragma unroll 2
            for (int k = 0; k < 256; k += 4) {
                float4 av = *(const float4*)(ap + k);
                float4 w0 = *(const float4*)(wp + (k    ) * 32);
                float4 w1 = *(const float4*)(wp + (k + 1) * 32);
                float4 w2 = *(const float4*)(wp + (k + 2) * 32);
                float4 w3 = *(const float4*)(wp + (k + 3) * 32);
                a0 = fmaf(av.x, w0.x, a0); a1 = fmaf(av.x, w0.y, a1);
                a2 = fmaf(av.x, w0.z, a2); a3 = fmaf(av.x, w0.w, a3);
                a0 = fmaf(av.y, w1.x, a0); a1 = fmaf(av.y, w1.y, a1);
                a2 = fmaf(av.y, w1.z, a2); a3 = fmaf(av.y, w1.w, a3);
                a0 = fmaf(av.z, w2.x, a0); a1 = fmaf(av.z, w2.y, a1);
                a2 = fmaf(av.z, w2.z, a2); a3 = fmaf(av.z, w2.w, a3);
                a0 = fmaf(av.w, w3.x, a0); a1 = fmaf(av.w, w3.y, a1);
                a2 = fmaf(av.w, w3.z, a2); a3 = fmaf(av.w, w3.w, a3);
            }
        }
        if (kh == 1)
            *(float4*)(gred + gr * 32 + cq * 4) = make_float4(a0, a1, a2, a3);
        __syncthreads();
        if (kh == 0) {
            float4 p = *(const float4*)(gred + gr * 32 + cq * 4);
            a0 += p.x + bg[cq * 4 + 0]; a1 += p.y + bg[cq * 4 + 1];
            a2 += p.z + bg[cq * 4 + 2]; a3 += p.w + bg[cq * 4 + 3];
            *(float4*)(gred + gr * 32 + cq * 4) = make_float4(a0, a1, a2, a3);
        }
        __syncthreads();

        // ---- LSTM cell update for this slice's 8 units x 32 rows; publish h ----
        if (tid < 256) {
            int r = tid >> 3, uu = tid & 7;
            float gi = gred[r * 32 +      uu];
            float gf = gred[r * 32 +  8 + uu];
            float gg = gred[r * 32 + 16 + uu];
            float go = gred[r * 32 + 24 + uu];
            cst = sigmoidf_(gf) * cst + sigmoidf_(gi) * tanhf(gg);
            float hn = sigmoidf_(go) * tanhf(cst);
            __hip_atomic_store(&g_h_ex[t & 1][rg][r][u0 + uu], hn,
                               __ATOMIC_RELAXED, __HIP_MEMORY_SCOPE_AGENT);
        }
        __builtin_amdgcn_fence(__ATOMIC_RELEASE, "agent");
        __syncthreads();
        if (tid == 0)
            __hip_atomic_store(&g_flag_h[rg][cb], t, __ATOMIC_RELEASE, __HIP_MEMORY_SCOPE_AGENT);

        // ---- gather full h(t); prefetch x(t+1) ----
        wait_group_flags(g_flag_h[rg], t, tid);
        {
            int r = tid >> 4, j0 = (tid & 15) * 16;
            const float* hp = &g_h_ex[t & 1][rg][r][j0];
            float* dh = act + r * ACT_STR + 256 + j0;
            #pragma unroll
            for (int j = 0; j < 16; ++j)
                dh[j] = __hip_atomic_load(hp + j, __ATOMIC_RELAXED, __HIP_MEMORY_SCOPE_AGENT);
            if (t + 1 < SEQT) {
                int j0x = (tid & 15) * 8;
                const T* ip = inp + ((size_t)(rg * MROWS + r) * SEQT + (t + 1)) * DX + j0x;
                float* dx = act + r * ACT_STR + 128 + j0x;
                #pragma unroll
                for (int j = 0; j < 8; ++j) dx[j] = ldf(ip + j);
            }
        }
        __syncthreads();

        // ---- heads: [32 rows x 256] @ [256 x 8 cols] ----
        float hacc = 0.0f;
        {
            const int hc = tid & 7;
            const float* ap = act + gr * ACT_STR + 256 + kh * 128;
            const float* wp = Wh + (kh * 128) * 8 + hc;
            #pragma unroll 4
            for (int k = 0; k < 128; ++k)
                hacc = fmaf(ap[k], wp[k * 8], hacc);
        }
        if (kh == 1) hscr[gr * 8 + (tid & 7)] = hacc;
        __syncthreads();
        if (kh == 0) {
            int hc = tid & 7;
            float tot = hacc + hscr[gr * 8 + hc] + bh[hc];
            size_t ob = ((size_t)(rg * MROWS + gr) * SEQT + t) * DZ + z0;
            if (hc < 4) {
                musig[gr * 8 + hc] = tot;
                stf(out + ob + hc, tot);
            } else {
                float sg = softplusf_(tot) + 1e-6f;
                musig[gr * 8 + hc] = sg;
                stf(out + OUT_SIG + ob + (hc - 4), sg);
            }
        }
        __syncthreads();

        // ---- z(t+1) = mu + sigma * eps[t]; publish ----
        if (t + 1 < SEQT) {
            if (tid < 128) {
                int r = tid >> 2, zc = tid & 3;
                float mu = musig[r * 8 + zc];
                float sg = musig[r * 8 + 4 + zc];
                float e  = ldf(eps + ((size_t)t * BATCH + (rg * MROWS + r)) * DZ + z0 + zc);
                float zv = fmaf(sg, e, mu);
                __hip_atomic_store(&g_z_ex[(t + 1) & 1][rg][r][z0 + zc], zv,
                                   __ATOMIC_RELAXED, __HIP_MEMORY_SCOPE_AGENT);
            }
            __builtin_amdgcn_fence(__ATOMIC_RELEASE, "agent");
            __syncthreads();
            if (tid == 0)
                __hip_atomic_store(&g_flag_z[rg][cb], t + 1, __ATOMIC_RELEASE, __HIP_MEMORY_SCOPE_AGENT);
        }
    }
}

template <typename T>
static void launch_persist(const int* flag, int want, void* const* d_in, void* d_out,
                           hipStream_t stream) {
    const T* a_inp  = (const T*)d_in[0];
    const T* a_K    = (const T*)d_in[1];
    const T* a_R    = (const T*)d_in[2];
    const T* a_b    = (const T*)d_in[3];
    const T* a_Wmu  = (const T*)d_in[4];
    const T* a_bmu  = (const T*)d_in[5];
    const T* a_Wsig = (const T*)d_in[6];
    const T* a_bsig = (const T*)d_in[7];
    const T* a_eps  = (const T*)d_in[8];
    T* a_out = (T*)d_out;
    const int* a_flag = flag;
    int a_want = want;
    void* args[] = { (void*)&a_flag, (void*)&a_want, (void*)&a_inp, (void*)&a_K,
                     (void*)&a_R, (void*)&a_b, (void*)&a_Wmu, (void*)&a_bmu,
                     (void*)&a_Wsig, (void*)&a_bsig, (void*)&a_eps, (void*)&a_out };
    hipError_t e = hipLaunchCooperativeKernel((void*)(&lstm_persist<T>),
                                              dim3(RG * CBN), dim3(NTHR),
                                              args, LDS_BYTES, stream);
    if (e != hipSuccess) {
        // Fallback: plain launch. 1 block/CU (146 KB LDS) x 256 blocks fills the
        // 256-CU chip, so all groups are de-facto co-resident.
        lstm_persist<T><<<dim3(RG * CBN), dim3(NTHR), LDS_BYTES, stream>>>(
            a_flag, a_want, a_inp, a_K, a_R, a_b, a_Wmu, a_bmu, a_Wsig, a_bsig,
            a_eps, a_out);
    }
}

extern "C" void kernel_launch(void* const* d_in, const int* in_sizes, int n_in,
                              void* d_out, int out_size, void* d_ws, size_t ws_size,
                              hipStream_t stream) {
    int* flag = (int*)d_ws;   // d_ws re-poisoned each call; probe rewrites it
    hipFuncSetAttribute((const void*)(&lstm_persist<__hip_bfloat16>),
                        hipFuncAttributeMaxDynamicSharedMemorySize, LDS_BYTES);
    hipFuncSetAttribute((const void*)(&lstm_persist<float>),
                        hipFuncAttributeMaxDynamicSharedMemorySize, LDS_BYTES);
    detect_dtype_kernel<<<1, 256, 0, stream>>>((const unsigned short*)d_in[3], flag);
    reset_flags_kernel<<<1, 256, 0, stream>>>();
    launch_persist<__hip_bfloat16>(flag, 0, d_in, d_out, stream);
    launch_persist<float>(flag, 1, d_in, d_out, stream);
}

// Round 3
// 34937.546 us; speedup vs baseline: 2.6584x; 2.6584x over previous
//
#include <hip/hip_runtime.h>
#include <hip/hip_bf16.h>
#include <math.h>

// R=4 rows-per-block weight-streaming LSTM. 64 blocks x 1024 threads.
// Each block owns 4 batch rows; activations (z|x|h) stay in its LDS, so there
// is NO inter-block communication. Weights are re-read from L2 each step, but
// each element only once per block (amortized over 4 rows).
// [Round 2 was an infra failure ("container failed twice"); this is a clean
//  resubmission of the same design to actually measure it.]

#define BATCH 256
#define SEQT  1024
#define DX    128
#define DZ    128
#define UNITS 256
#define G4    1024

#define RPB   4
#define NBLK  (BATCH / RPB)   // 64
#define NTHR  1024

__device__ __forceinline__ float ldf(const float* p) { return *p; }
__device__ __forceinline__ float ldf(const __hip_bfloat16* p) { return __bfloat162float(*p); }
__device__ __forceinline__ void stf(float* p, float v) { *p = v; }
__device__ __forceinline__ void stf(__hip_bfloat16* p, float v) { *p = __float2bfloat16(v); }

__device__ __forceinline__ float2 ld2(const float* p) { return *(const float2*)p; }
__device__ __forceinline__ float2 ld2(const __hip_bfloat16* p) {
    unsigned int u = *(const unsigned int*)p;   // two bf16 in one dword
    union { unsigned int i; float f; } a, b;
    a.i = u << 16; b.i = u & 0xffff0000u;
    return make_float2(a.f, b.f);
}

__device__ __forceinline__ float sigmoidf_(float x) { return 1.0f / (1.0f + expf(-x)); }
__device__ __forceinline__ float softplusf_(float x) {
    float ax = fabsf(x);
    return fmaxf(x, 0.0f) + log1pf(expf(-ax));
}

// Probe: bias holds 1024 small values. bf16 words all have exponent < 127;
// fp32 low-mantissa words are ~random -> some word has exponent >= 127.
__global__ void detect_dtype_kernel(const unsigned short* __restrict__ bias_words,
                                    int* __restrict__ flag) {
    __shared__ int any_big;
    if (threadIdx.x == 0) any_big = 0;
    __syncthreads();
    int local = 0;
    for (int i = threadIdx.x; i < 1024; i += 256) {
        unsigned short w = bias_words[i];
        int e = (w >> 7) & 0xFF;
        if (e >= 127) local = 1;
    }
    if (local) atomicOr(&any_big, 1);
    __syncthreads();
    if (threadIdx.x == 0) flag[0] = any_big;
}

template <typename T>
__global__ __launch_bounds__(NTHR) void lstm_r4(
    const int* __restrict__ flag, int want,
    const T* __restrict__ inp,   // [B][T][DX]
    const T* __restrict__ K,     // [256][1024] gate cols: i,f,g,o blocks of 256
    const T* __restrict__ R,     // [256][1024]
    const T* __restrict__ bias,  // [1024]
    const T* __restrict__ Wmu,   // [256][128]
    const T* __restrict__ bmu,   // [128]
    const T* __restrict__ Wsig,  // [256][128]
    const T* __restrict__ bsig,  // [128]
    const T* __restrict__ eps,   // [T-1][B][DZ]
    T* __restrict__ out)         // mu [B][T][DZ] then sigma [B][T][DZ]
{
    if (flag[0] != want) return;

    __shared__ __align__(16) float act[RPB][516];        // [ z(128) | x(128) | h(256) ] + pad
    __shared__ __align__(16) float gred[RPB][1024];      // gate partials -> totals
    __shared__ __align__(16) float hred[3][RPB][256];    // head partials (ks=1..3)
    __shared__ __align__(16) float mus[RPB][128];
    __shared__ __align__(16) float sgs[RPB][128];

    const int tid = threadIdx.x;
    const int b0  = blockIdx.x * RPB;

    // ---- gate-phase coords: tid = kh*512 + g*128 + q ----
    const int q  = tid & 127;
    const int g  = (tid >> 7) & 3;
    const int kh = tid >> 9;                 // 0: K (zx), 1: R (h)
    const int c0 = g * 256 + q * 2;          // gate column pair base
    const T* wp0 = ((kh == 0) ? K : R) + c0;
    const int acol0 = kh * 256;              // act col base for this k-half
    float2 bg = make_float2(0.0f, 0.0f);
    if (kh == 0) bg = ld2(bias + c0);

    // ---- head-phase coords: tid = ks*256 + hc ----
    const int hc = tid & 255;                // 0..127 mu, 128..255 sigma
    const int ks = tid >> 8;                 // 4-way k-split (64 each)
    const T* hw0 = (hc < 128) ? (Wmu  + (size_t)(ks * 64) * DZ + hc)
                              : (Wsig + (size_t)(ks * 64) * DZ + (hc - 128));
    float bh = 0.0f;
    if (ks == 0) bh = (hc < 128) ? ldf(bmu + hc) : ldf(bsig + hc - 128);

    // ---- cell coords: one (row, unit) per thread ----
    const int cu = tid & 255;
    const int cr = tid >> 8;
    float cst = 0.0f;

    // ---- init: z=h=0, stage x(0) ----
    for (int i = tid; i < RPB * 512; i += NTHR) act[i >> 9][i & 511] = 0.0f;
    __syncthreads();
    if (tid < 512) {
        int r = tid >> 7, xc = tid & 127;
        act[r][128 + xc] = ldf(inp + (size_t)(b0 + r) * SEQT * DX + xc);
    }
    __syncthreads();

    const size_t OUT_SIG = (size_t)BATCH * SEQT * DZ;

    for (int t = 0; t < SEQT; ++t) {
        // ---- prefetch eps[t] / x(t+1) into a register; consumed in phase 6 ----
        float pf = 0.0f;
        if (t + 1 < SEQT) {
            if (tid < 512) {
                int r = tid >> 7, zc = tid & 127;
                pf = ldf(eps + ((size_t)t * BATCH + b0 + r) * DZ + zc);
            } else {
                int j = tid & 511, r = j >> 7, xc = j & 127;
                pf = ldf(inp + ((size_t)(b0 + r) * SEQT + (t + 1)) * DX + xc);
            }
        }

        // ---- gates: acc[r] (2 cols) over this thread's 256-k half ----
        float2 acc[RPB];
        #pragma unroll
        for (int r = 0; r < RPB; ++r) acc[r] = make_float2(0.0f, 0.0f);
        {
            const T* wp = wp0;
            #pragma unroll 2
            for (int k = 0; k < 256; k += 4) {
                float2 w0 = ld2(wp);
                float2 w1 = ld2(wp + G4);
                float2 w2 = ld2(wp + 2 * G4);
                float2 w3 = ld2(wp + 3 * G4);
                wp += 4 * G4;
                float4 a0 = *(const float4*)&act[0][acol0 + k];
                float4 a1 = *(const float4*)&act[1][acol0 + k];
                float4 a2 = *(const float4*)&act[2][acol0 + k];
                float4 a3 = *(const float4*)&act[3][acol0 + k];
                acc[0].x = fmaf(a0.x, w0.x, fmaf(a0.y, w1.x, fmaf(a0.z, w2.x, fmaf(a0.w, w3.x, acc[0].x))));
                acc[0].y = fmaf(a0.x, w0.y, fmaf(a0.y, w1.y, fmaf(a0.z, w2.y, fmaf(a0.w, w3.y, acc[0].y))));
                acc[1].x = fmaf(a1.x, w0.x, fmaf(a1.y, w1.x, fmaf(a1.z, w2.x, fmaf(a1.w, w3.x, acc[1].x))));
                acc[1].y = fmaf(a1.x, w0.y, fmaf(a1.y, w1.y, fmaf(a1.z, w2.y, fmaf(a1.w, w3.y, acc[1].y))));
                acc[2].x = fmaf(a2.x, w0.x, fmaf(a2.y, w1.x, fmaf(a2.z, w2.x, fmaf(a2.w, w3.x, acc[2].x))));
                acc[2].y = fmaf(a2.x, w0.y, fmaf(a2.y, w1.y, fmaf(a2.z, w2.y, fmaf(a2.w, w3.y, acc[2].y))));
                acc[3].x = fmaf(a3.x, w0.x, fmaf(a3.y, w1.x, fmaf(a3.z, w2.x, fmaf(a3.w, w3.x, acc[3].x))));
                acc[3].y = fmaf(a3.x, w0.y, fmaf(a3.y, w1.y, fmaf(a3.z, w2.y, fmaf(a3.w, w3.y, acc[3].y))));
            }
        }
        if (kh == 1) {
            #pragma unroll
            for (int r = 0; r < RPB; ++r)
                *(float2*)&gred[r][c0] = acc[r];
        }
        __syncthreads();                               // B1: partials visible
        if (kh == 0) {
            #pragma unroll
            for (int r = 0; r < RPB; ++r) {
                float2 p = *(const float2*)&gred[r][c0];
                p.x += acc[r].x + bg.x;
                p.y += acc[r].y + bg.y;
                *(float2*)&gred[r][c0] = p;
            }
        }
        __syncthreads();                               // B2: totals visible

        // ---- cell update; write h into act ----
        {
            float gi = gred[cr][cu];
            float gf = gred[cr][256 + cu];
            float gg = gred[cr][512 + cu];
            float go = gred[cr][768 + cu];
            cst = sigmoidf_(gf) * cst + sigmoidf_(gi) * tanhf(gg);
            act[cr][256 + cu] = sigmoidf_(go) * tanhf(cst);
        }
        __syncthreads();                               // B3: h visible

        // ---- heads: 4 rows x 1 col over this thread's 64-k slice ----
        float hacc[RPB] = {0.0f, 0.0f, 0.0f, 0.0f};
        {
            const T* hw = hw0;
            const int a0c = 256 + ks * 64;
            #pragma unroll 2
            for (int kk = 0; kk < 64; kk += 4) {
                float w0 = ldf(hw);
                float w1 = ldf(hw + DZ);
                float w2 = ldf(hw + 2 * DZ);
                float w3 = ldf(hw + 3 * DZ);
                hw += 4 * DZ;
                float4 a0 = *(const float4*)&act[0][a0c + kk];
                float4 a1 = *(const float4*)&act[1][a0c + kk];
                float4 a2 = *(const float4*)&act[2][a0c + kk];
                float4 a3 = *(const float4*)&act[3][a0c + kk];
                hacc[0] = fmaf(a0.x, w0, fmaf(a0.y, w1, fmaf(a0.z, w2, fmaf(a0.w, w3, hacc[0]))));
                hacc[1] = fmaf(a1.x, w0, fmaf(a1.y, w1, fmaf(a1.z, w2, fmaf(a1.w, w3, hacc[1]))));
                hacc[2] = fmaf(a2.x, w0, fmaf(a2.y, w1, fmaf(a2.z, w2, fmaf(a2.w, w3, hacc[2]))));
                hacc[3] = fmaf(a3.x, w0, fmaf(a3.y, w1, fmaf(a3.z, w2, fmaf(a3.w, w3, hacc[3]))));
            }
        }
        if (ks >= 1) {
            #pragma unroll
            for (int r = 0; r < RPB; ++r) hred[ks - 1][r][hc] = hacc[r];
        }
        __syncthreads();                               // B4: head partials visible
        if (ks == 0) {
            #pragma unroll
            for (int r = 0; r < RPB; ++r) {
                float tot = hacc[r] + hred[0][r][hc] + hred[1][r][hc] + hred[2][r][hc] + bh;
                size_t ob = ((size_t)(b0 + r) * SEQT + t) * DZ;
                if (hc < 128) {
                    mus[r][hc] = tot;
                    stf(out + ob + hc, tot);
                } else {
                    float sg = softplusf_(tot) + 1e-6f;
                    sgs[r][hc - 128] = sg;
                    stf(out + OUT_SIG + ob + (hc - 128), sg);
                }
            }
        }
        __syncthreads();                               // B5: mus/sgs visible

        // ---- z(t+1) = mu + sigma*eps; stage x(t+1) ----
        if (t + 1 < SEQT) {
            if (tid < 512) {
                int r = tid >> 7, zc = tid & 127;
                act[r][zc] = fmaf(sgs[r][zc], pf, mus[r][zc]);
            } else {
                int j = tid & 511, r = j >> 7, xc = j & 127;
                act[r][128 + xc] = pf;
            }
        }
        __syncthreads();                               // B6: act stable for next step
    }
}

template <typename T>
static void launch_main(const int* flag, int want, void* const* d_in, void* d_out,
                        hipStream_t stream) {
    lstm_r4<T><<<NBLK, NTHR, 0, stream>>>(
        flag, want,
        (const T*)d_in[0], (const T*)d_in[1], (const T*)d_in[2], (const T*)d_in[3],
        (const T*)d_in[4], (const T*)d_in[5], (const T*)d_in[6], (const T*)d_in[7],
        (const T*)d_in[8], (T*)d_out);
}

extern "C" void kernel_launch(void* const* d_in, const int* in_sizes, int n_in,
                              void* d_out, int out_size, void* d_ws, size_t ws_size,
                              hipStream_t stream) {
    int* flag = (int*)d_ws;   // d_ws re-poisoned each call; probe rewrites it
    detect_dtype_kernel<<<1, 256, 0, stream>>>((const unsigned short*)d_in[3], flag);
    launch_main<__hip_bfloat16>(flag, 0, d_in, d_out, stream);
    launch_main<float>(flag, 1, d_in, d_out, stream);
}

// Round 5
// 30866.660 us; speedup vs baseline: 3.0090x; 1.1319x over previous
//
#include <hip/hip_runtime.h>
#include <hip/hip_bf16.h>
#include <math.h>

// R=1 weight-streaming LSTM, latency-hiding build (de-risked: static LDS only,
// no dynamic shared memory, no hipFuncSetAttribute).
// 256 blocks (one batch row each) x 1024 threads (16 waves/CU = 4/SIMD).
// Weight loads are dword-packed column pairs (64-lane coalesced, 256B/instr).
// Activations/partials in LDS; c-state in registers. Weights re-streamed from
// L2 each step (1.18 MB bf16 / 2.36 MB fp32 per block per step).

#define BATCH 256
#define SEQT  1024
#define DX    128
#define DZ    128
#define UNITS 256
#define G4    1024
#define NTHR  1024

__device__ __forceinline__ float ldf(const float* p) { return *p; }
__device__ __forceinline__ float ldf(const __hip_bfloat16* p) { return __bfloat162float(*p); }
__device__ __forceinline__ void stf(float* p, float v) { *p = v; }
__device__ __forceinline__ void stf(__hip_bfloat16* p, float v) { *p = __float2bfloat16(v); }

// load a packed column pair (2 consecutive elements) as 2 floats
__device__ __forceinline__ float2 ldpair(const float* p) { return *(const float2*)p; }
__device__ __forceinline__ float2 ldpair(const __hip_bfloat16* p) {
    unsigned int u = *(const unsigned int*)p;       // elem0 | elem1<<16 (LE)
    union { unsigned int i; float f; } a, b;
    a.i = u << 16; b.i = u & 0xffff0000u;
    return make_float2(a.f, b.f);
}

__device__ __forceinline__ float sigmoidf_(float x) { return 1.0f / (1.0f + expf(-x)); }
__device__ __forceinline__ float softplusf_(float x) {
    float ax = fabsf(x);
    return fmaxf(x, 0.0f) + log1pf(expf(-ax));
}

// Probe: bias holds 1024 small values. bf16 words all have exponent < 127;
// fp32 low-mantissa words are ~random -> some word has exponent >= 127.
__global__ void detect_dtype_kernel(const unsigned short* __restrict__ bias_words,
                                    int* __restrict__ flag) {
    __shared__ int any_big;
    if (threadIdx.x == 0) any_big = 0;
    __syncthreads();
    int local = 0;
    for (int i = threadIdx.x; i < 1024; i += 256) {
        unsigned short w = bias_words[i];
        int e = (w >> 7) & 0xFF;
        if (e >= 127) local = 1;
    }
    if (local) atomicOr(&any_big, 1);
    __syncthreads();
    if (threadIdx.x == 0) flag[0] = any_big;
}

template <typename T>
__global__ __launch_bounds__(NTHR) void lstm_r1(
    const int* __restrict__ flag, int want,
    const T* __restrict__ inp,   // [B][T][DX]
    const T* __restrict__ K,     // [256][1024] gate cols: i,f,g,o blocks of 256
    const T* __restrict__ Rw,    // [256][1024]
    const T* __restrict__ bias,  // [1024]
    const T* __restrict__ Wmu,   // [256][128]
    const T* __restrict__ bmu,   // [128]
    const T* __restrict__ Wsig,  // [256][128]
    const T* __restrict__ bsig,  // [128]
    const T* __restrict__ eps,   // [T-1][B][DZ]
    T* __restrict__ out)         // mu [B][T][DZ] then sigma [B][T][DZ]
{
    if (flag[0] != want) return;

    __shared__ __align__(16) float act[512];      // z(128) | x(128) | h(256)
    __shared__ __align__(16) float gA[1024];      // gate partial, K half
    __shared__ __align__(16) float gB[1024];      // gate partial, R half
    __shared__ __align__(16) float hred[8][256];  // head partials
    __shared__ __align__(16) float mus[128];
    __shared__ __align__(16) float sgs[128];

    const int tid = threadIdx.x;
    const int b   = blockIdx.x;

    // ---- gate-phase coords ----
    const int cp = tid & 511;        // column pair: cols 2cp, 2cp+1
    const int kh = tid >> 9;         // 0: zx @ K, 1: h @ Rw
    const T* wp0 = ((kh == 0) ? K : Rw) + 2 * cp;
    const float* actp = act + kh * 256;

    // ---- head-phase coords: 128 col-pairs x 8 k-slices ----
    const int cp2 = tid & 127;       // combined [mu(0..63)|sig(64..127)] pair idx
    const int ks  = tid >> 7;        // 0..7, 32 k each
    const T* hw0 = (cp2 < 64) ? (Wmu + 2 * cp2) : (Wsig + 2 * cp2 - 128);
    hw0 += (size_t)(32 * ks) * DZ;

    // ---- per-(unit/col) scalars for threads 0..255 ----
    float b_i = 0.f, b_f = 0.f, b_g = 0.f, b_o = 0.f, bh = 0.f;
    if (tid < 256) {
        b_i = ldf(bias + tid);
        b_f = ldf(bias + 256 + tid);
        b_g = ldf(bias + 512 + tid);
        b_o = ldf(bias + 768 + tid);
        bh  = (tid < 128) ? ldf(bmu + tid) : ldf(bsig + tid - 128);
    }
    float cst = 0.0f;

    // ---- running global pointers for this row ----
    const T* inpp = inp + (size_t)b * SEQT * DX;        // x(t)
    const T* epsp = eps + (size_t)b * DZ;               // eps[t] row b
    T* outmu = out + (size_t)b * SEQT * DZ;
    T* outsg = outmu + (size_t)BATCH * SEQT * DZ;

    // ---- init activations: z=h=0, stage x(0) ----
    if (tid < 512) act[tid] = 0.0f;
    __syncthreads();
    if (tid < 128) act[128 + tid] = ldf(inpp + tid);
    __syncthreads();

    for (int t = 0; t < SEQT; ++t) {
        // ---- prefetch eps[t] (tid<128) / x(t+1) (tid 128..255) ----
        float pf = 0.0f;
        if (t + 1 < SEQT) {
            if (tid < 128)       pf = ldf(epsp + tid);
            else if (tid < 256)  pf = ldf(inpp + DX + (tid - 128));
        }

        // ---- gates: column pair (2cp, 2cp+1), this thread's 256-k half ----
        float2 acc = make_float2(0.0f, 0.0f);
        {
            const T* wp = wp0;
            #pragma unroll 2
            for (int k0 = 0; k0 < 256; k0 += 4) {
                float4 av = *(const float4*)(actp + k0);
                float2 w0 = ldpair(wp);
                float2 w1 = ldpair(wp + G4);
                float2 w2 = ldpair(wp + 2 * G4);
                float2 w3 = ldpair(wp + 3 * G4);
                wp += 4 * G4;
                acc.x = fmaf(av.x, w0.x, fmaf(av.y, w1.x, fmaf(av.z, w2.x, fmaf(av.w, w3.x, acc.x))));
                acc.y = fmaf(av.x, w0.y, fmaf(av.y, w1.y, fmaf(av.z, w2.y, fmaf(av.w, w3.y, acc.y))));
            }
        }
        {
            float* gdst = kh ? gB : gA;
            *(float2*)&gdst[2 * cp] = acc;
        }
        __syncthreads();                     // B1: gate partials visible

        // ---- cell update (threads 0..255); write h into act ----
        if (tid < 256) {
            float ai = gA[tid]       + gB[tid]       + b_i;
            float af = gA[256 + tid] + gB[256 + tid] + b_f;
            float ag = gA[512 + tid] + gB[512 + tid] + b_g;
            float ao = gA[768 + tid] + gB[768 + tid] + b_o;
            cst = sigmoidf_(af) * cst + sigmoidf_(ai) * tanhf(ag);
            act[256 + tid] = sigmoidf_(ao) * tanhf(cst);
        }
        __syncthreads();                     // B2: h visible

        // ---- heads: col pair over 32-k slice ----
        float2 hacc = make_float2(0.0f, 0.0f);
        {
            const float* hap = act + 256 + 32 * ks;
            const T* hw = hw0;
            #pragma unroll
            for (int k0 = 0; k0 < 32; k0 += 4) {
                float4 av = *(const float4*)(hap + k0);
                float2 w0 = ldpair(hw);
                float2 w1 = ldpair(hw + DZ);
                float2 w2 = ldpair(hw + 2 * DZ);
                float2 w3 = ldpair(hw + 3 * DZ);
                hw += 4 * DZ;
                hacc.x = fmaf(av.x, w0.x, fmaf(av.y, w1.x, fmaf(av.z, w2.x, fmaf(av.w, w3.x, hacc.x))));
                hacc.y = fmaf(av.x, w0.y, fmaf(av.y, w1.y, fmaf(av.z, w2.y, fmaf(av.w, w3.y, hacc.y))));
            }
        }
        *(float2*)&hred[ks][2 * cp2] = hacc;
        __syncthreads();                     // B3: head partials visible

        // ---- head totals, out store, mus/sgs (threads 0..255) ----
        if (tid < 256) {
            float tot = bh;
            #pragma unroll
            for (int s = 0; s < 8; ++s) tot += hred[s][tid];
            if (tid < 128) {
                mus[tid] = tot;
                stf(outmu + tid, tot);
            } else {
                float sg = softplusf_(tot) + 1e-6f;
                sgs[tid - 128] = sg;
                stf(outsg + (tid - 128), sg);
            }
        }
        __syncthreads();                     // B4: mus/sgs visible

        // ---- z(t+1) = mu + sigma*eps; stage x(t+1) ----
        if (t + 1 < SEQT) {
            if (tid < 128)       act[tid] = fmaf(sgs[tid], pf, mus[tid]);
            else if (tid < 256)  act[128 + (tid - 128)] = pf;
        }
        __syncthreads();                     // B5: act stable for next gate loop

        inpp  += DX;
        epsp  += (size_t)BATCH * DZ;
        outmu += DZ;
        outsg += DZ;
    }
}

template <typename T>
static void launch_main(const int* flag, int want, void* const* d_in, void* d_out,
                        hipStream_t stream) {
    lstm_r1<T><<<BATCH, NTHR, 0, stream>>>(
        flag, want,
        (const T*)d_in[0], (const T*)d_in[1], (const T*)d_in[2], (const T*)d_in[3],
        (const T*)d_in[4], (const T*)d_in[5], (const T*)d_in[6], (const T*)d_in[7],
        (const T*)d_in[8], (T*)d_out);
}

extern "C" void kernel_launch(void* const* d_in, const int* in_sizes, int n_in,
                              void* d_out, int out_size, void* d_ws, size_t ws_size,
                              hipStream_t stream) {
    int* flag = (int*)d_ws;   // d_ws re-poisoned each call; probe rewrites it
    detect_dtype_kernel<<<1, 256, 0, stream>>>((const unsigned short*)d_in[3], flag);
    launch_main<__hip_bfloat16>(flag, 0, d_in, d_out, stream);
    launch_main<float>(flag, 1, d_in, d_out, stream);
}